// Round 3
// baseline (5826.096 us; speedup 1.0000x reference)
//
#include <hip/hip_runtime.h>
#include <cstdint>
#include <cstddef>

#define NODES   55
#define BGRAPH  16384
#define NTOT    (BGRAPH*NODES)    // 901120
#define INCH    13
#define HID     32
#define ETOT    (4*NTOT)          // 3604480
#define NCHUNK  (NTOT/1024)       // 880 exact

typedef _Float16 f16;
typedef _Float16 f16x8 __attribute__((ext_vector_type(8))); // 16B

__device__ __forceinline__ float selu_f(float v){
  const float s  = 1.0507009873554805f;
  const float sa = 1.7580993408473766f;   // scale*alpha
  return v > 0.f ? s*v : sa*(__expf(v)-1.f);
}

// ---------------- CSR build ----------------
__global__ void k_hist(const int* __restrict__ dst, int* __restrict__ deg){
  int e = blockIdx.x*256 + threadIdx.x;
  if (e < ETOT) atomicAdd(&deg[dst[e]], 1);
}

__global__ void k_scan1(const int* __restrict__ deg, int* __restrict__ part){
  __shared__ int sd[256];
  int b = blockIdx.x, t = threadIdx.x;
  const int4* p = (const int4*)(deg + b*1024);
  int4 v = p[t];
  sd[t] = v.x+v.y+v.z+v.w;
  __syncthreads();
  for (int o=128;o>0;o>>=1){ if (t<o) sd[t]+=sd[t+o]; __syncthreads(); }
  if (t==0) part[b] = sd[0];
}

__global__ void k_scan2(int* __restrict__ part, int nc){
  __shared__ int sd[1024];
  int t = threadIdx.x;
  int orig = (t<nc) ? part[t] : 0;
  sd[t] = orig;
  __syncthreads();
  for (int o=1;o<1024;o<<=1){
    int v = (t>=o) ? sd[t-o] : 0;
    __syncthreads();
    sd[t] += v;
    __syncthreads();
  }
  if (t<nc) part[t] = sd[t] - orig;   // exclusive
}

__global__ void k_scan3(const int* __restrict__ deg, const int* __restrict__ part,
                        int* __restrict__ off){
  __shared__ int sd[256];
  int b = blockIdx.x, t = threadIdx.x;
  const int4* p = (const int4*)(deg + b*1024);
  int4 v = p[t];
  int s = v.x+v.y+v.z+v.w;
  sd[t] = s;
  __syncthreads();
  for (int o=1;o<256;o<<=1){
    int val = (t>=o) ? sd[t-o] : 0;
    __syncthreads();
    sd[t] += val;
    __syncthreads();
  }
  int base = part[b] + sd[t] - s;     // exclusive prefix for this thread
  int i = b*1024 + t*4;
  off[i]   = base;
  off[i+1] = base + v.x;
  off[i+2] = base + v.x + v.y;
  off[i+3] = base + v.x + v.y + v.z;
  if (b==0 && t==0) off[NTOT] = ETOT;
}

__global__ void k_fill(const int* __restrict__ src, const int* __restrict__ dst,
                       int* __restrict__ cur, int* __restrict__ csr){
  int e = blockIdx.x*256 + threadIdx.x;
  if (e >= ETOT) return;
  int d = dst[e];
  int pos = atomicAdd(&cur[d], 1);
  csr[pos] = src[e];
}

// ---------------- fused SAGE layer 0 ----------------
// Phase 1: gather mean(x[nbr]) into LDS (stride 13, conflict-free: gcd(13,32)=1)
// Phase 2: thread = node, transform + selu, write fp16 h & jk
__global__ __launch_bounds__(256,4) void k_layer0(
    const float* __restrict__ x,
    const int* __restrict__ off, const int* __restrict__ csr,
    const float* __restrict__ wl0, const float* __restrict__ bl0,
    const float* __restrict__ wr0,
    f16* __restrict__ hout, f16* __restrict__ jk)
{
  __shared__ float AG[256*INCH];   // 13.3 KB
  int t = threadIdx.x;
  int base = blockIdx.x*256;
  int c = t & 31;
  int half = t >> 5;
  for (int sub=0; sub<32; sub++){
    int nl = sub*8 + half;
    int node = base + nl;
    int s0 = off[node], s1 = off[node+1];
    if (c < INCH){
      float s = 0.f;
      for (int e=s0;e<s1;e++){
        int sn = csr[e];
        s += x[(size_t)sn*INCH + c];
      }
      int cnt = s1-s0; if (cnt<1) cnt=1;
      AG[nl*INCH+c] = s/(float)cnt;
    }
  }
  __syncthreads();
  int node = base + t;
  const float* xr = x + (size_t)node*INCH;
  float acc[HID];
  #pragma unroll
  for (int oc=0;oc<HID;oc++) acc[oc] = bl0[oc];
  #pragma unroll
  for (int cc=0;cc<INCH;cc++){
    float xc = xr[cc];
    float mc = AG[t*INCH+cc];
    #pragma unroll
    for (int oc=0;oc<HID;oc++)
      acc[oc] = fmaf(xc, wr0[cc*HID+oc], fmaf(mc, wl0[cc*HID+oc], acc[oc]));
  }
  f16x8* ho = (f16x8*)(hout + (size_t)node*HID);
  f16x8* jo = (f16x8*)(jk   + (size_t)node*HID);
  #pragma unroll
  for (int j=0;j<4;j++){
    f16x8 v;
    #pragma unroll
    for (int r=0;r<8;r++) v[r] = (f16)selu_f(acc[8*j+r]);
    ho[j] = v; jo[j] = v;
  }
}

// ---------------- fused SAGE layers 1..4 ----------------
// Phase 1: 32 lanes per node gather mean(hin[nbr]) -> LDS tile (stride 33)
// Phase 2: thread = node: acc = agg@wl + bl + h@wr, selu, jk max. Streams c in
// chunks of 8 so only acc[32]+chunk live (no scratch; 128-VGPR cap via lb(256,4)).
__global__ __launch_bounds__(256,4) void k_layer(
    const f16* __restrict__ hin,
    const int* __restrict__ off, const int* __restrict__ csr,
    const float* __restrict__ wl, const float* __restrict__ bl,
    const float* __restrict__ wr,
    f16* __restrict__ hout, f16* __restrict__ jk)
{
  __shared__ float AG[256*33];   // 33.8 KB
  int t = threadIdx.x;
  int base = blockIdx.x*256;
  int c = t & 31;
  int half = t >> 5;
  for (int sub=0; sub<32; sub++){
    int nl = sub*8 + half;
    int node = base + nl;
    int s0 = off[node], s1 = off[node+1];
    float s = 0.f;
    for (int e=s0;e<s1;e++){
      int sn = csr[e];
      s += (float)hin[(size_t)sn*HID + c];
    }
    int cnt = s1-s0; if (cnt<1) cnt=1;
    AG[nl*33+c] = s/(float)cnt;
  }
  __syncthreads();
  int node = base + t;
  const f16x8* h8 = (const f16x8*)(hin + (size_t)node*HID);
  float acc[HID];
  #pragma unroll
  for (int oc=0;oc<HID;oc++) acc[oc] = bl[oc];
  #pragma unroll
  for (int j=0;j<4;j++){
    f16x8 vh = h8[j];
    #pragma unroll
    for (int r=0;r<8;r++){
      int cc = 8*j+r;
      float hc = (float)vh[r];
      float mc = AG[t*33+cc];
      #pragma unroll
      for (int oc=0;oc<HID;oc++)
        acc[oc] = fmaf(hc, wr[cc*HID+oc], fmaf(mc, wl[cc*HID+oc], acc[oc]));
    }
  }
  f16x8* ho = (f16x8*)(hout + (size_t)node*HID);
  f16x8* jo = (f16x8*)(jk   + (size_t)node*HID);
  #pragma unroll
  for (int j=0;j<4;j++){
    f16x8 vcur = jo[j];
    f16x8 vh2, vj;
    #pragma unroll
    for (int r=0;r<8;r++){
      float sv = selu_f(acc[8*j+r]);
      vh2[r] = (f16)sv;
      vj[r]  = (f16)fmaxf((float)vcur[r], sv);
    }
    ho[j] = vh2; jo[j] = vj;
  }
}

// ---------------- attention + head, one block per graph ----------------
__global__ __launch_bounds__(256) void k_attn(
    const f16* __restrict__ jk, const float* __restrict__ x,
    const int* __restrict__ shuf,
    const float* __restrict__ wq, const float* __restrict__ bq,
    const float* __restrict__ wk, const float* __restrict__ bk,
    const float* __restrict__ wv, const float* __restrict__ bv,
    const float* __restrict__ wo, const float* __restrict__ bo,
    const float* __restrict__ wfc, const float* __restrict__ bfc,
    float* __restrict__ out)
{
  __shared__ float H[NODES*33];
  __shared__ float K[NODES*33];
  __shared__ float V[NODES*33];
  __shared__ float Wq[HID*HID];
  __shared__ float Wo[HID*HID];
  __shared__ float Wfc[192*6];
  __shared__ float Qs[6*33];
  __shared__ float S[6*56];
  __shared__ float O[6*33];
  __shared__ float SO[192];
  __shared__ float part[96];
  __shared__ float M[NODES];
  __shared__ int order[8];
  __shared__ int sel[6];

  int g = blockIdx.x, t = threadIdx.x;
  for (int i=t; i<HID*HID; i+=256){ Wq[i]=wq[i]; Wo[i]=wo[i]; }
  for (int i=t; i<192*6;   i+=256){ Wfc[i]=wfc[i]; }
  {
    const f16x8* j8 = (const f16x8*)(jk + (size_t)g*NODES*HID);
    for (int i=t; i<NODES*HID/8; i+=256){     // 220 vectors of 8
      f16x8 v = j8[i];
      int node = i >> 2, c0 = (i & 3)*8;
      #pragma unroll
      for (int r=0;r<8;r++) H[node*33 + c0 + r] = selu_f((float)v[r]);
    }
  }
  if (t < NODES) M[t] = x[(size_t)(g*NODES+t)*INCH + (INCH-3)];
  __syncthreads();
  if (t == 0){
    int c = 0;
    for (int n=0;n<NODES;n++) if (M[n] > 0.5f && c < 6) order[c++] = n;
  }
  __syncthreads();
  if (t < 6) sel[t] = order[shuf[g*6 + t]];
  __syncthreads();

  // K and V: lane = node, wave-uniform output-channel group -> scalar weights
  {
    int k = t & 63;
    int ocg = __builtin_amdgcn_readfirstlane(t >> 6);   // 0..3, wave-uniform
    const float* wkp = wk + ocg*8;
    const float* wvp = wv + ocg*8;
    if (k < NODES){
      float ak[8], av[8];
      #pragma unroll
      for (int j=0;j<8;j++){ ak[j]=bk[ocg*8+j]; av[j]=bv[ocg*8+j]; }
      #pragma unroll
      for (int c=0;c<HID;c++){
        float hv = H[k*33+c];
        #pragma unroll
        for (int j=0;j<8;j++){
          ak[j] = fmaf(hv, wkp[c*HID+j], ak[j]);
          av[j] = fmaf(hv, wvp[c*HID+j], av[j]);
        }
      }
      #pragma unroll
      for (int j=0;j<8;j++){ K[k*33+ocg*8+j]=ak[j]; V[k*33+ocg*8+j]=av[j]; }
    }
  }
  // Q: 6 queries x 32 channels
  if (t < 192){
    int q = t>>5, oc = t&31;
    int node = sel[q];
    float a = bq[oc];
    #pragma unroll
    for (int c=0;c<HID;c++) a = fmaf(H[node*33+c], Wq[c*HID+oc], a);
    Qs[q*33+oc] = a;
  }
  __syncthreads();

  // scores = Q.K^T / sqrt(32)
  for (int idx=t; idx<6*NODES; idx+=256){
    int q = idx % 6, k = idx / 6;
    float a = 0.f;
    #pragma unroll
    for (int c=0;c<HID;c++) a = fmaf(Qs[q*33+c], K[k*33+c], a);
    S[q*56+k] = a * 0.17677669529663687f;
  }
  __syncthreads();

  // softmax over 55 keys: 32-lane group per query
  if (t < 192){
    int q = t>>5, l = t&31;
    float v0 = (l      < NODES) ? S[q*56+l]    : -1e30f;
    float v1 = (l+32   < NODES) ? S[q*56+l+32] : -1e30f;
    float mx = fmaxf(v0, v1);
    #pragma unroll
    for (int o=16;o>0;o>>=1) mx = fmaxf(mx, __shfl_xor(mx, o, 32));
    float p0 = (l    < NODES) ? __expf(v0-mx) : 0.f;
    float p1 = (l+32 < NODES) ? __expf(v1-mx) : 0.f;
    float sm = p0 + p1;
    #pragma unroll
    for (int o=16;o>0;o>>=1) sm += __shfl_xor(sm, o, 32);
    float inv = 1.f/sm;
    if (l    < NODES) S[q*56+l]    = p0*inv;
    if (l+32 < NODES) S[q*56+l+32] = p1*inv;
  }
  __syncthreads();

  // attn @ V
  if (t < 192){
    int q = t>>5, oc = t&31;
    float a = 0.f;
    for (int k=0;k<NODES;k++) a = fmaf(S[q*56+k], V[k*33+oc], a);
    O[q*33+oc] = a;
  }
  __syncthreads();

  // @ wo + bo, selu
  if (t < 192){
    int q = t>>5, oc = t&31;
    float a = bo[oc];
    #pragma unroll
    for (int c=0;c<HID;c++) a = fmaf(O[q*33+c], Wo[c*HID+oc], a);
    SO[t] = selu_f(a);   // t == q*32+oc == flat reshape index
  }
  __syncthreads();

  // final FC: 6 outputs = SO[192] . Wfc[:,j]
  if (t < 96){
    int j = t % 6, pp = t / 6;   // 16 partials per output
    float a = 0.f;
    #pragma unroll
    for (int r=0;r<12;r++) a = fmaf(SO[pp*12+r], Wfc[(pp*12+r)*6+j], a);
    part[pp*6+j] = a;
  }
  __syncthreads();
  if (t < 6){
    float a = bfc[t];
    #pragma unroll
    for (int pp=0;pp<16;pp++) a += part[pp*6+t];
    out[g*6+t] = a;
  }
}

extern "C" void kernel_launch(void* const* d_in, const int* in_sizes, int n_in,
                              void* d_out, int out_size, void* d_ws, size_t ws_size,
                              hipStream_t stream)
{
  const float* x   = (const float*)d_in[0];
  const int*   eix = (const int*)d_in[1];
  const int*   shf = (const int*)d_in[2];
  const float* wl0 = (const float*)d_in[3];
  const float* bl0 = (const float*)d_in[4];
  const float* wr0 = (const float*)d_in[5];
  const float* wl  = (const float*)d_in[6];
  const float* bl  = (const float*)d_in[7];
  const float* wr  = (const float*)d_in[8];
  const float* wq  = (const float*)d_in[9];
  const float* bq  = (const float*)d_in[10];
  const float* wk  = (const float*)d_in[11];
  const float* bk  = (const float*)d_in[12];
  const float* wv  = (const float*)d_in[13];
  const float* bv  = (const float*)d_in[14];
  const float* wo  = (const float*)d_in[15];
  const float* bo  = (const float*)d_in[16];
  const float* wfc = (const float*)d_in[17];
  const float* bfc = (const float*)d_in[18];
  float* out = (float*)d_out;

  const int* esrc = eix;
  const int* edst = eix + ETOT;

  // workspace carve — total ~195 MB
  char* p = (char*)d_ws;
  auto carve = [&](size_t bytes){ void* r = (void*)p; p += (bytes + 255) & ~(size_t)255; return r; };
  int*   deg  = (int*)carve(sizeof(int)*NTOT);          // reused as `cur` for k_fill
  int*   off  = (int*)carve(sizeof(int)*(NTOT+1));
  int*   part = (int*)carve(sizeof(int)*1024);
  int*   csr  = (int*)carve(sizeof(int)*(size_t)ETOT);
  f16*   h_a  = (f16*)carve(2*(size_t)NTOT*HID);
  f16*   h_b  = (f16*)carve(2*(size_t)NTOT*HID);
  f16*   jk16 = (f16*)carve(2*(size_t)NTOT*HID);

  hipMemsetAsync(deg, 0, sizeof(int)*NTOT, stream);
  k_hist <<<ETOT/256,  256, 0, stream>>>(edst, deg);
  k_scan1<<<NCHUNK,    256, 0, stream>>>(deg, part);
  k_scan2<<<1,        1024, 0, stream>>>(part, NCHUNK);
  k_scan3<<<NCHUNK,    256, 0, stream>>>(deg, part, off);
  // reuse deg as the fill cursor
  hipMemcpyAsync(deg, off, sizeof(int)*NTOT, hipMemcpyDeviceToDevice, stream);
  k_fill <<<ETOT/256,  256, 0, stream>>>(esrc, edst, deg, csr);

  k_layer0<<<NTOT/256, 256, 0, stream>>>(x, off, csr, wl0, bl0, wr0, h_a, jk16);
  f16* hc = h_a; f16* hn = h_b;
  for (int l=0; l<4; l++){
    k_layer<<<NTOT/256, 256, 0, stream>>>(hc, off, csr,
                                          wl + l*HID*HID, bl + l*HID, wr + l*HID*HID,
                                          hn, jk16);
    f16* tmp = hc; hc = hn; hn = tmp;
  }
  k_attn<<<BGRAPH, 256, 0, stream>>>(jk16, x, shf,
                                     wq, bq, wk, bk, wv, bv, wo, bo, wfc, bfc, out);
}

// Round 4
// 4927.525 us; speedup vs baseline: 1.1824x; 1.1824x over previous
//
#include <hip/hip_runtime.h>
#include <cstdint>
#include <cstddef>

#define NODES   55
#define BGRAPH  16384
#define NTOT    (BGRAPH*NODES)    // 901120
#define INCH    13
#define HID     32
#define ETOT    (4*NTOT)          // 3604480
#define NCHUNK  (NTOT/1024)       // 880 exact

typedef _Float16 f16;
typedef _Float16 f16x4 __attribute__((ext_vector_type(4))); // 8B
typedef _Float16 f16x8 __attribute__((ext_vector_type(8))); // 16B

__device__ __forceinline__ float selu_f(float v){
  const float s  = 1.0507009873554805f;
  const float sa = 1.7580993408473766f;   // scale*alpha
  return v > 0.f ? s*v : sa*(__expf(v)-1.f);
}

// ---------------- CSR build ----------------
__global__ void k_hist(const int* __restrict__ dst, int* __restrict__ deg){
  int e = blockIdx.x*256 + threadIdx.x;
  if (e < ETOT) atomicAdd(&deg[dst[e]], 1);
}

__global__ void k_scan1(const int* __restrict__ deg, int* __restrict__ part){
  __shared__ int sd[256];
  int b = blockIdx.x, t = threadIdx.x;
  const int4* p = (const int4*)(deg + b*1024);
  int4 v = p[t];
  sd[t] = v.x+v.y+v.z+v.w;
  __syncthreads();
  for (int o=128;o>0;o>>=1){ if (t<o) sd[t]+=sd[t+o]; __syncthreads(); }
  if (t==0) part[b] = sd[0];
}

__global__ void k_scan2(int* __restrict__ part, int nc){
  __shared__ int sd[1024];
  int t = threadIdx.x;
  int orig = (t<nc) ? part[t] : 0;
  sd[t] = orig;
  __syncthreads();
  for (int o=1;o<1024;o<<=1){
    int v = (t>=o) ? sd[t-o] : 0;
    __syncthreads();
    sd[t] += v;
    __syncthreads();
  }
  if (t<nc) part[t] = sd[t] - orig;   // exclusive
}

__global__ void k_scan3(const int* __restrict__ deg, const int* __restrict__ part,
                        int* __restrict__ off){
  __shared__ int sd[256];
  int b = blockIdx.x, t = threadIdx.x;
  const int4* p = (const int4*)(deg + b*1024);
  int4 v = p[t];
  int s = v.x+v.y+v.z+v.w;
  sd[t] = s;
  __syncthreads();
  for (int o=1;o<256;o<<=1){
    int val = (t>=o) ? sd[t-o] : 0;
    __syncthreads();
    sd[t] += val;
    __syncthreads();
  }
  int base = part[b] + sd[t] - s;     // exclusive prefix for this thread
  int i = b*1024 + t*4;
  off[i]   = base;
  off[i+1] = base + v.x;
  off[i+2] = base + v.x + v.y;
  off[i+3] = base + v.x + v.y + v.z;
  if (b==0 && t==0) off[NTOT] = ETOT;
}

__global__ void k_fill(const int* __restrict__ src, const int* __restrict__ dst,
                       int* __restrict__ cur, int* __restrict__ csr){
  int e = blockIdx.x*256 + threadIdx.x;
  if (e >= ETOT) return;
  int d = dst[e];
  int pos = atomicAdd(&cur[d], 1);
  csr[pos] = src[e];
}

// ---------------- fused SAGE layer 0 ----------------
__global__ __launch_bounds__(256,6) void k_layer0(
    const float* __restrict__ x,
    const int* __restrict__ off, const int* __restrict__ csr,
    const float* __restrict__ wl0, const float* __restrict__ bl0,
    const float* __restrict__ wr0,
    f16* __restrict__ hout, f16* __restrict__ jkout)
{
  __shared__ float AG0[256*INCH];   // 13.3 KB, stride 13 (odd -> conflict-free)
  __shared__ f16   ST[256*34];      // 17.0 KB staging
  int t = threadIdx.x;
  int base = blockIdx.x*256;
  // phase 1: mean gather (16 lanes/node, batched-4 edges)
  int c = t & 15, qn = t >> 4;
  for (int p=0; p<16; p++){
    int nl = p*16 + qn;
    int node = base + nl;
    int s0 = off[node], s1 = off[node+1];
    if (c < INCH){
      float s = 0.f;
      for (int e=s0; e<s1; e+=4){
        int e1 = (e+1<s1)? e+1 : e;
        int e2 = (e+2<s1)? e+2 : e;
        int e3 = (e+3<s1)? e+3 : e;
        int i0=csr[e], i1=csr[e1], i2=csr[e2], i3=csr[e3];
        float v0 = x[(size_t)i0*INCH + c];
        float v1 = x[(size_t)i1*INCH + c];
        float v2 = x[(size_t)i2*INCH + c];
        float v3 = x[(size_t)i3*INCH + c];
        s += v0;
        if (e+1<s1) s += v1;
        if (e+2<s1) s += v2;
        if (e+3<s1) s += v3;
      }
      int cnt = s1-s0; if (cnt<1) cnt=1;
      AG0[nl*INCH+c] = s/(float)cnt;
    }
  }
  __syncthreads();
  // phase 2: thread = node
  int node = base + t;
  const float* xr = x + (size_t)node*INCH;
  float acc[HID];
  #pragma unroll
  for (int oc=0;oc<HID;oc++) acc[oc] = bl0[oc];
  #pragma unroll
  for (int cc=0;cc<INCH;cc++){
    float xc = xr[cc];
    float mc = AG0[t*INCH+cc];
    #pragma unroll
    for (int oc=0;oc<HID;oc++)
      acc[oc] = fmaf(xc, wr0[cc*HID+oc], fmaf(mc, wl0[cc*HID+oc], acc[oc]));
  }
  // stage selu(h) into own row
  f16* myrow = ST + t*34;
  #pragma unroll
  for (int oc=0;oc<HID;oc++) myrow[oc] = (f16)selu_f(acc[oc]);
  __syncthreads();
  // coalesced write: h = jk = staged value
  const uint32_t* STd = (const uint32_t*)ST;
  uint4* ho4 = (uint4*)hout;
  uint4* jo4 = (uint4*)jkout;
  int gbase = blockIdx.x*1024;
  #pragma unroll
  for (int k=0;k<4;k++){
    int cch = t + 256*k;          // 0..1023 local 16B chunk
    int n = cch>>2, m = cch&3;
    int d = n*17 + m*4;
    uint4 u;
    u.x=STd[d]; u.y=STd[d+1]; u.z=STd[d+2]; u.w=STd[d+3];
    ho4[gbase+cch] = u;
    jo4[gbase+cch] = u;
  }
}

// ---------------- fused SAGE layers 1..4 ----------------
// Phase 1: 8 lanes/node, f16x4 loads, batched-4 edges -> mean into f16 LDS (stride 34)
// Phase 2: thread = node, acc = agg@wl + bl + h@wr (scalar weights), selu, stage,
// then lane-coalesced h/jk writes.
__global__ __launch_bounds__(256,6) void k_layer(
    const f16* __restrict__ hin,
    const int* __restrict__ off, const int* __restrict__ csr,
    const float* __restrict__ wl, const float* __restrict__ bl,
    const float* __restrict__ wr,
    f16* __restrict__ hout, f16* __restrict__ jkio)
{
  __shared__ f16 AG[256*34];   // 17.0 KB (mean, then reused as output stage)
  int t = threadIdx.x;
  int base = blockIdx.x*256;
  int l = t & 7, qn = t >> 3;       // lane-in-node (4 ch), node-in-pass
  for (int p=0; p<8; p++){
    int nl = p*32 + qn;
    int node = base + nl;
    int s0 = off[node], s1 = off[node+1];
    float a0=0.f,a1=0.f,a2=0.f,a3=0.f;
    for (int e=s0; e<s1; e+=4){
      int e1 = (e+1<s1)? e+1 : e;
      int e2 = (e+2<s1)? e+2 : e;
      int e3 = (e+3<s1)? e+3 : e;
      int i0=csr[e], i1=csr[e1], i2=csr[e2], i3=csr[e3];
      f16x4 v0 = *(const f16x4*)(hin + (size_t)i0*HID + 4*l);
      f16x4 v1 = *(const f16x4*)(hin + (size_t)i1*HID + 4*l);
      f16x4 v2 = *(const f16x4*)(hin + (size_t)i2*HID + 4*l);
      f16x4 v3 = *(const f16x4*)(hin + (size_t)i3*HID + 4*l);
      a0 += (float)v0[0]; a1 += (float)v0[1]; a2 += (float)v0[2]; a3 += (float)v0[3];
      if (e+1<s1){ a0+=(float)v1[0]; a1+=(float)v1[1]; a2+=(float)v1[2]; a3+=(float)v1[3]; }
      if (e+2<s1){ a0+=(float)v2[0]; a1+=(float)v2[1]; a2+=(float)v2[2]; a3+=(float)v2[3]; }
      if (e+3<s1){ a0+=(float)v3[0]; a1+=(float)v3[1]; a2+=(float)v3[2]; a3+=(float)v3[3]; }
    }
    int cnt = s1-s0; if (cnt<1) cnt=1;
    float inv = 1.f/(float)cnt;
    f16* row = AG + nl*34 + 4*l;
    row[0]=(f16)(a0*inv); row[1]=(f16)(a1*inv);
    row[2]=(f16)(a2*inv); row[3]=(f16)(a3*inv);
  }
  __syncthreads();
  // phase 2: thread = node
  int node = base + t;
  const f16x8* h8 = (const f16x8*)(hin + (size_t)node*HID);
  const f16*   ag = AG + t*34;
  float acc[HID];
  #pragma unroll
  for (int oc=0;oc<HID;oc++) acc[oc] = bl[oc];
  #pragma unroll
  for (int j=0;j<4;j++){
    f16x8 vh = h8[j];
    #pragma unroll
    for (int r=0;r<8;r++){
      int cc = 8*j+r;
      float hc = (float)vh[r];
      float mc = (float)ag[cc];
      #pragma unroll
      for (int oc=0;oc<HID;oc++)
        acc[oc] = fmaf(hc, wr[cc*HID+oc], fmaf(mc, wl[cc*HID+oc], acc[oc]));
    }
  }
  // stage selu(h) into OWN row (only this thread read this row -> no barrier needed)
  f16* myrow = AG + t*34;
  #pragma unroll
  for (int oc=0;oc<HID;oc++) myrow[oc] = (f16)selu_f(acc[oc]);
  __syncthreads();
  // coalesced h write + jk read-max-write
  const uint32_t* STd = (const uint32_t*)AG;
  uint4* ho4 = (uint4*)hout;
  uint4* jo4 = (uint4*)jkio;
  int gbase = blockIdx.x*1024;
  #pragma unroll
  for (int k=0;k<4;k++){
    int cch = t + 256*k;
    int n = cch>>2, m = cch&3;
    int d = n*17 + m*4;
    union { uint4 u; f16 h[8]; } hv, jv;
    hv.u.x=STd[d]; hv.u.y=STd[d+1]; hv.u.z=STd[d+2]; hv.u.w=STd[d+3];
    jv.u = jo4[gbase+cch];
    #pragma unroll
    for (int r=0;r<8;r++){
      float a = (float)jv.h[r], b = (float)hv.h[r];
      jv.h[r] = (f16)fmaxf(a, b);
    }
    ho4[gbase+cch] = hv.u;
    jo4[gbase+cch] = jv.u;
  }
}

// ---------------- attention + head, one block per graph ----------------
__global__ __launch_bounds__(256) void k_attn(
    const f16* __restrict__ jk, const float* __restrict__ x,
    const int* __restrict__ shuf,
    const float* __restrict__ wq, const float* __restrict__ bq,
    const float* __restrict__ wk, const float* __restrict__ bk,
    const float* __restrict__ wv, const float* __restrict__ bv,
    const float* __restrict__ wo, const float* __restrict__ bo,
    const float* __restrict__ wfc, const float* __restrict__ bfc,
    float* __restrict__ out)
{
  __shared__ float H[NODES*33];
  __shared__ float K[NODES*33];
  __shared__ float V[NODES*33];
  __shared__ float Wq[HID*HID];
  __shared__ float Wo[HID*HID];
  __shared__ float Wfc[192*6];
  __shared__ float Qs[6*33];
  __shared__ float S[6*56];
  __shared__ float O[6*33];
  __shared__ float SO[192];
  __shared__ float part[96];
  __shared__ float M[NODES];
  __shared__ int order[8];
  __shared__ int sel[6];

  int g = blockIdx.x, t = threadIdx.x;
  for (int i=t; i<HID*HID; i+=256){ Wq[i]=wq[i]; Wo[i]=wo[i]; }
  for (int i=t; i<192*6;   i+=256){ Wfc[i]=wfc[i]; }
  {
    const f16x8* j8 = (const f16x8*)(jk + (size_t)g*NODES*HID);
    for (int i=t; i<NODES*HID/8; i+=256){     // 220 vectors of 8
      f16x8 v = j8[i];
      int node = i >> 2, c0 = (i & 3)*8;
      #pragma unroll
      for (int r=0;r<8;r++) H[node*33 + c0 + r] = selu_f((float)v[r]);
    }
  }
  if (t < NODES) M[t] = x[(size_t)(g*NODES+t)*INCH + (INCH-3)];
  __syncthreads();
  if (t == 0){
    int c = 0;
    for (int n=0;n<NODES;n++) if (M[n] > 0.5f && c < 6) order[c++] = n;
  }
  __syncthreads();
  if (t < 6) sel[t] = order[shuf[g*6 + t]];
  __syncthreads();

  // K and V: lane = node, wave-uniform output-channel group -> scalar weights
  {
    int k = t & 63;
    int ocg = __builtin_amdgcn_readfirstlane(t >> 6);   // 0..3, wave-uniform
    const float* wkp = wk + ocg*8;
    const float* wvp = wv + ocg*8;
    if (k < NODES){
      float ak[8], av[8];
      #pragma unroll
      for (int j=0;j<8;j++){ ak[j]=bk[ocg*8+j]; av[j]=bv[ocg*8+j]; }
      #pragma unroll
      for (int c=0;c<HID;c++){
        float hv = H[k*33+c];
        #pragma unroll
        for (int j=0;j<8;j++){
          ak[j] = fmaf(hv, wkp[c*HID+j], ak[j]);
          av[j] = fmaf(hv, wvp[c*HID+j], av[j]);
        }
      }
      #pragma unroll
      for (int j=0;j<8;j++){ K[k*33+ocg*8+j]=ak[j]; V[k*33+ocg*8+j]=av[j]; }
    }
  }
  // Q: 6 queries x 32 channels
  if (t < 192){
    int q = t>>5, oc = t&31;
    int node = sel[q];
    float a = bq[oc];
    #pragma unroll
    for (int c=0;c<HID;c++) a = fmaf(H[node*33+c], Wq[c*HID+oc], a);
    Qs[q*33+oc] = a;
  }
  __syncthreads();

  // scores = Q.K^T / sqrt(32)
  for (int idx=t; idx<6*NODES; idx+=256){
    int q = idx % 6, k = idx / 6;
    float a = 0.f;
    #pragma unroll
    for (int c=0;c<HID;c++) a = fmaf(Qs[q*33+c], K[k*33+c], a);
    S[q*56+k] = a * 0.17677669529663687f;
  }
  __syncthreads();

  // softmax over 55 keys: 32-lane group per query
  if (t < 192){
    int q = t>>5, l = t&31;
    float v0 = (l      < NODES) ? S[q*56+l]    : -1e30f;
    float v1 = (l+32   < NODES) ? S[q*56+l+32] : -1e30f;
    float mx = fmaxf(v0, v1);
    #pragma unroll
    for (int o=16;o>0;o>>=1) mx = fmaxf(mx, __shfl_xor(mx, o, 32));
    float p0 = (l    < NODES) ? __expf(v0-mx) : 0.f;
    float p1 = (l+32 < NODES) ? __expf(v1-mx) : 0.f;
    float sm = p0 + p1;
    #pragma unroll
    for (int o=16;o>0;o>>=1) sm += __shfl_xor(sm, o, 32);
    float inv = 1.f/sm;
    if (l    < NODES) S[q*56+l]    = p0*inv;
    if (l+32 < NODES) S[q*56+l+32] = p1*inv;
  }
  __syncthreads();

  // attn @ V
  if (t < 192){
    int q = t>>5, oc = t&31;
    float a = 0.f;
    for (int k=0;k<NODES;k++) a = fmaf(S[q*56+k], V[k*33+oc], a);
    O[q*33+oc] = a;
  }
  __syncthreads();

  // @ wo + bo, selu
  if (t < 192){
    int q = t>>5, oc = t&31;
    float a = bo[oc];
    #pragma unroll
    for (int c=0;c<HID;c++) a = fmaf(O[q*33+c], Wo[c*HID+oc], a);
    SO[t] = selu_f(a);   // t == q*32+oc == flat reshape index
  }
  __syncthreads();

  // final FC: 6 outputs = SO[192] . Wfc[:,j]
  if (t < 96){
    int j = t % 6, pp = t / 6;   // 16 partials per output
    float a = 0.f;
    #pragma unroll
    for (int r=0;r<12;r++) a = fmaf(SO[pp*12+r], Wfc[(pp*12+r)*6+j], a);
    part[pp*6+j] = a;
  }
  __syncthreads();
  if (t < 6){
    float a = bfc[t];
    #pragma unroll
    for (int pp=0;pp<16;pp++) a += part[pp*6+t];
    out[g*6+t] = a;
  }
}

extern "C" void kernel_launch(void* const* d_in, const int* in_sizes, int n_in,
                              void* d_out, int out_size, void* d_ws, size_t ws_size,
                              hipStream_t stream)
{
  const float* x   = (const float*)d_in[0];
  const int*   eix = (const int*)d_in[1];
  const int*   shf = (const int*)d_in[2];
  const float* wl0 = (const float*)d_in[3];
  const float* bl0 = (const float*)d_in[4];
  const float* wr0 = (const float*)d_in[5];
  const float* wl  = (const float*)d_in[6];
  const float* bl  = (const float*)d_in[7];
  const float* wr  = (const float*)d_in[8];
  const float* wq  = (const float*)d_in[9];
  const float* bq  = (const float*)d_in[10];
  const float* wk  = (const float*)d_in[11];
  const float* bk  = (const float*)d_in[12];
  const float* wv  = (const float*)d_in[13];
  const float* bv  = (const float*)d_in[14];
  const float* wo  = (const float*)d_in[15];
  const float* bo  = (const float*)d_in[16];
  const float* wfc = (const float*)d_in[17];
  const float* bfc = (const float*)d_in[18];
  float* out = (float*)d_out;

  const int* esrc = eix;
  const int* edst = eix + ETOT;

  // workspace carve — total ~195 MB
  char* p = (char*)d_ws;
  auto carve = [&](size_t bytes){ void* r = (void*)p; p += (bytes + 255) & ~(size_t)255; return r; };
  int*   deg  = (int*)carve(sizeof(int)*NTOT);          // reused as `cur` for k_fill
  int*   off  = (int*)carve(sizeof(int)*(NTOT+1));
  int*   part = (int*)carve(sizeof(int)*1024);
  int*   csr  = (int*)carve(sizeof(int)*(size_t)ETOT);
  f16*   h_a  = (f16*)carve(2*(size_t)NTOT*HID);
  f16*   h_b  = (f16*)carve(2*(size_t)NTOT*HID);
  f16*   jk16 = (f16*)carve(2*(size_t)NTOT*HID);

  hipMemsetAsync(deg, 0, sizeof(int)*NTOT, stream);
  k_hist <<<ETOT/256,  256, 0, stream>>>(edst, deg);
  k_scan1<<<NCHUNK,    256, 0, stream>>>(deg, part);
  k_scan2<<<1,        1024, 0, stream>>>(part, NCHUNK);
  k_scan3<<<NCHUNK,    256, 0, stream>>>(deg, part, off);
  // reuse deg as the fill cursor
  hipMemcpyAsync(deg, off, sizeof(int)*NTOT, hipMemcpyDeviceToDevice, stream);
  k_fill <<<ETOT/256,  256, 0, stream>>>(esrc, edst, deg, csr);

  k_layer0<<<NTOT/256, 256, 0, stream>>>(x, off, csr, wl0, bl0, wr0, h_a, jk16);
  f16* hc = h_a; f16* hn = h_b;
  for (int l=0; l<4; l++){
    k_layer<<<NTOT/256, 256, 0, stream>>>(hc, off, csr,
                                          wl + l*HID*HID, bl + l*HID, wr + l*HID*HID,
                                          hn, jk16);
    f16* tmp = hc; hc = hn; hn = tmp;
  }
  k_attn<<<BGRAPH, 256, 0, stream>>>(jk16, x, shf,
                                     wq, bq, wk, bk, wv, bv, wo, bo, wfc, bfc, out);
}

// Round 5
// 3830.369 us; speedup vs baseline: 1.5210x; 1.2864x over previous
//
#include <hip/hip_runtime.h>
#include <cstdint>
#include <cstddef>

#define NODES   55
#define BGRAPH  16384
#define NTOT    (BGRAPH*NODES)    // 901120
#define INCH    13
#define HID     32
#define ETOT    (4*NTOT)          // 3604480
#define NCHUNK  (NTOT/1024)       // 880 exact
#define NPB     128               // nodes per block (layer kernels)

typedef _Float16 f16;
typedef _Float16 f16x4 __attribute__((ext_vector_type(4))); // 8B
typedef _Float16 f16x8 __attribute__((ext_vector_type(8))); // 16B

__device__ __forceinline__ float selu_f(float v){
  const float s  = 1.0507009873554805f;
  const float sa = 1.7580993408473766f;   // scale*alpha
  return v > 0.f ? s*v : sa*(__expf(v)-1.f);
}

// ---------------- CSR build ----------------
__global__ void k_hist(const int* __restrict__ dst, int* __restrict__ deg){
  int e = blockIdx.x*256 + threadIdx.x;
  if (e < ETOT) atomicAdd(&deg[dst[e]], 1);
}

__global__ void k_scan1(const int* __restrict__ deg, int* __restrict__ part){
  __shared__ int sd[256];
  int b = blockIdx.x, t = threadIdx.x;
  const int4* p = (const int4*)(deg + b*1024);
  int4 v = p[t];
  sd[t] = v.x+v.y+v.z+v.w;
  __syncthreads();
  for (int o=128;o>0;o>>=1){ if (t<o) sd[t]+=sd[t+o]; __syncthreads(); }
  if (t==0) part[b] = sd[0];
}

__global__ void k_scan2(int* __restrict__ part, int nc){
  __shared__ int sd[1024];
  int t = threadIdx.x;
  int orig = (t<nc) ? part[t] : 0;
  sd[t] = orig;
  __syncthreads();
  for (int o=1;o<1024;o<<=1){
    int v = (t>=o) ? sd[t-o] : 0;
    __syncthreads();
    sd[t] += v;
    __syncthreads();
  }
  if (t<nc) part[t] = sd[t] - orig;   // exclusive
}

__global__ void k_scan3(const int* __restrict__ deg, const int* __restrict__ part,
                        int* __restrict__ off){
  __shared__ int sd[256];
  int b = blockIdx.x, t = threadIdx.x;
  const int4* p = (const int4*)(deg + b*1024);
  int4 v = p[t];
  int s = v.x+v.y+v.z+v.w;
  sd[t] = s;
  __syncthreads();
  for (int o=1;o<256;o<<=1){
    int val = (t>=o) ? sd[t-o] : 0;
    __syncthreads();
    sd[t] += val;
    __syncthreads();
  }
  int base = part[b] + sd[t] - s;     // exclusive prefix for this thread
  int i = b*1024 + t*4;
  off[i]   = base;
  off[i+1] = base + v.x;
  off[i+2] = base + v.x + v.y;
  off[i+3] = base + v.x + v.y + v.z;
  if (b==0 && t==0) off[NTOT] = ETOT;
}

// packed entry: src (20 bits) | dst_local-within-128 (7 bits) << 20
__global__ void k_fill(const int* __restrict__ src, const int* __restrict__ dst,
                       int* __restrict__ cur, uint32_t* __restrict__ csrp){
  int e = blockIdx.x*256 + threadIdx.x;
  if (e >= ETOT) return;
  int d = dst[e];
  int pos = atomicAdd(&cur[d], 1);
  csrp[pos] = (uint32_t)src[e] | (((uint32_t)d & 127u) << 20);
}

// ---------------- fused SAGE layer 0 (edge-parallel gather) ----------------
__global__ __launch_bounds__(256,8) void k_layer0(
    const float* __restrict__ x,
    const int* __restrict__ off, const uint32_t* __restrict__ csrp,
    const float* __restrict__ wl0, const float* __restrict__ bl0,
    const float* __restrict__ wr0,
    f16* __restrict__ hout, f16* __restrict__ jkout)
{
  __shared__ float AG0[NPB*INCH];   // 6.7 KB fp32 accumulators
  __shared__ f16   ST0[NPB*34];     // 8.7 KB output staging
  int t = threadIdx.x;
  int base = blockIdx.x*NPB;
  for (int i=t; i<NPB*INCH; i+=256) AG0[i] = 0.f;
  __syncthreads();

  int e0 = off[base], e1 = off[base+NPB];
  int slot = t >> 4, c = t & 15;        // 16 slots, lane=channel
  if (c < INCH){
    for (int eb=e0; eb<e1; eb+=64){
      int a0 = eb+slot, a1 = a0+16, a2 = a0+32, a3 = a0+48;
      bool q0=a0<e1, q1=a1<e1, q2=a2<e1, q3=a3<e1;
      int m0=q0?a0:e1-1, m1=q1?a1:e1-1, m2=q2?a2:e1-1, m3=q3?a3:e1-1;
      uint32_t k0=csrp[m0], k1=csrp[m1], k2=csrp[m2], k3=csrp[m3];
      float v0 = x[(size_t)((k0&0xFFFFFu)*INCH + c)];
      float v1 = x[(size_t)((k1&0xFFFFFu)*INCH + c)];
      float v2 = x[(size_t)((k2&0xFFFFFu)*INCH + c)];
      float v3 = x[(size_t)((k3&0xFFFFFu)*INCH + c)];
      atomicAdd(AG0 + ((k0>>20)&127u)*INCH + c, q0?v0:0.f);
      atomicAdd(AG0 + ((k1>>20)&127u)*INCH + c, q1?v1:0.f);
      atomicAdd(AG0 + ((k2>>20)&127u)*INCH + c, q2?v2:0.f);
      atomicAdd(AG0 + ((k3>>20)&127u)*INCH + c, q3?v3:0.f);
    }
  }
  __syncthreads();

  // phase 2: node = base+(t&127), ochalf = t>>7 (wave-uniform)
  int nl = t & 127;
  int node = base + nl;
  int oc0 = __builtin_amdgcn_readfirstlane((t>>7)*16);
  int cnt = off[node+1]-off[node]; if (cnt<1) cnt=1;
  float inv = 1.f/(float)cnt;
  const float* xr = x + (size_t)node*INCH;
  float acc[16];
  #pragma unroll
  for (int j=0;j<16;j++) acc[j] = bl0[oc0+j];
  #pragma unroll
  for (int cc=0;cc<INCH;cc++){
    float xc = xr[cc];
    float mc = AG0[nl*INCH+cc]*inv;
    #pragma unroll
    for (int j=0;j<16;j++)
      acc[j] = fmaf(xc, wr0[cc*HID+oc0+j], fmaf(mc, wl0[cc*HID+oc0+j], acc[j]));
  }
  #pragma unroll
  for (int j=0;j<16;j++) ST0[nl*34 + oc0 + j] = (f16)selu_f(acc[j]);
  __syncthreads();

  const uint32_t* STd = (const uint32_t*)ST0;
  uint4* ho4 = (uint4*)hout;
  uint4* jo4 = (uint4*)jkout;
  int gbase = blockIdx.x*(NPB*HID/8);   // 512 16B-chunks per block
  #pragma unroll
  for (int k=0;k<2;k++){
    int cch = t + 256*k;
    int n = cch>>2, m = cch&3;
    int d = n*17 + m*4;
    uint4 u;
    u.x=STd[d]; u.y=STd[d+1]; u.z=STd[d+2]; u.w=STd[d+3];
    ho4[gbase+cch] = u;
    jo4[gbase+cch] = u;
  }
}

// ---------------- fused SAGE layers 1..4 (edge-parallel gather) ----------------
__global__ __launch_bounds__(256,8) void k_layer(
    const f16* __restrict__ hin,
    const int* __restrict__ off, const uint32_t* __restrict__ csrp,
    const float* __restrict__ wl, const float* __restrict__ bl,
    const float* __restrict__ wr,
    f16* __restrict__ hout, f16* __restrict__ jkio)
{
  __shared__ float AGf[NPB*33];    // 16.9 KB fp32 accumulators (reused as f16 staging)
  int t = threadIdx.x;
  int base = blockIdx.x*NPB;
  for (int i=t; i<NPB*33; i+=256) AGf[i] = 0.f;
  __syncthreads();

  int e0 = off[base], e1 = off[base+NPB];
  int slot = t >> 3, l = t & 7;        // 32 edge-slots, 8 lanes (4ch each) per edge
  for (int eb=e0; eb<e1; eb+=128){
    int a0 = eb+slot, a1 = a0+32, a2 = a0+64, a3 = a0+96;
    bool q0=a0<e1, q1=a1<e1, q2=a2<e1, q3=a3<e1;
    int m0=q0?a0:e1-1, m1=q1?a1:e1-1, m2=q2?a2:e1-1, m3=q3?a3:e1-1;
    uint32_t k0=csrp[m0], k1=csrp[m1], k2=csrp[m2], k3=csrp[m3];
    f16x4 g0 = *(const f16x4*)(hin + (size_t)((k0&0xFFFFFu)*32u + 4u*l));
    f16x4 g1 = *(const f16x4*)(hin + (size_t)((k1&0xFFFFFu)*32u + 4u*l));
    f16x4 g2 = *(const f16x4*)(hin + (size_t)((k2&0xFFFFFu)*32u + 4u*l));
    f16x4 g3 = *(const f16x4*)(hin + (size_t)((k3&0xFFFFFu)*32u + 4u*l));
    float* d0 = AGf + ((k0>>20)&127u)*33 + 4*l;
    float* d1 = AGf + ((k1>>20)&127u)*33 + 4*l;
    float* d2 = AGf + ((k2>>20)&127u)*33 + 4*l;
    float* d3 = AGf + ((k3>>20)&127u)*33 + 4*l;
    #pragma unroll
    for (int j=0;j<4;j++) atomicAdd(d0+j, q0?(float)g0[j]:0.f);
    #pragma unroll
    for (int j=0;j<4;j++) atomicAdd(d1+j, q1?(float)g1[j]:0.f);
    #pragma unroll
    for (int j=0;j<4;j++) atomicAdd(d2+j, q2?(float)g2[j]:0.f);
    #pragma unroll
    for (int j=0;j<4;j++) atomicAdd(d3+j, q3?(float)g3[j]:0.f);
  }
  __syncthreads();

  // phase 2: node = base+(t&127), ochalf = t>>7 (wave-uniform -> scalar weights)
  int nl = t & 127;
  int node = base + nl;
  int oc0 = __builtin_amdgcn_readfirstlane((t>>7)*16);
  int cnt = off[node+1]-off[node]; if (cnt<1) cnt=1;
  float inv = 1.f/(float)cnt;
  const f16x8* h8 = (const f16x8*)(hin + (size_t)node*HID);
  float acc[16];
  #pragma unroll
  for (int j=0;j<16;j++) acc[j] = bl[oc0+j];
  #pragma unroll
  for (int jj=0;jj<4;jj++){
    f16x8 vh = h8[jj];
    #pragma unroll
    for (int r=0;r<8;r++){
      int cc = 8*jj+r;
      float hc = (float)vh[r];
      float mc = AGf[nl*33+cc]*inv;
      #pragma unroll
      for (int j=0;j<16;j++)
        acc[j] = fmaf(hc, wr[cc*HID+oc0+j], fmaf(mc, wl[cc*HID+oc0+j], acc[j]));
    }
  }
  __syncthreads();   // all AGf reads done -> safe to alias as staging
  f16* ST = (f16*)AGf;
  #pragma unroll
  for (int j=0;j<16;j++) ST[nl*34 + oc0 + j] = (f16)selu_f(acc[j]);
  __syncthreads();

  const uint32_t* STd = (const uint32_t*)AGf;
  uint4* ho4 = (uint4*)hout;
  uint4* jo4 = (uint4*)jkio;
  int gbase = blockIdx.x*(NPB*HID/8);
  #pragma unroll
  for (int k=0;k<2;k++){
    int cch = t + 256*k;
    int n = cch>>2, m = cch&3;
    int d = n*17 + m*4;
    union { uint4 u; f16 hh[8]; } hv, jv;
    hv.u.x=STd[d]; hv.u.y=STd[d+1]; hv.u.z=STd[d+2]; hv.u.w=STd[d+3];
    jv.u = jo4[gbase+cch];
    #pragma unroll
    for (int r=0;r<8;r++){
      float a = (float)jv.hh[r], b = (float)hv.hh[r];
      jv.hh[r] = (f16)fmaxf(a, b);
    }
    ho4[gbase+cch] = hv.u;
    jo4[gbase+cch] = jv.u;
  }
}

// ---------------- attention + head, one block per graph ----------------
__global__ __launch_bounds__(256) void k_attn(
    const f16* __restrict__ jk, const float* __restrict__ x,
    const int* __restrict__ shuf,
    const float* __restrict__ wq, const float* __restrict__ bq,
    const float* __restrict__ wk, const float* __restrict__ bk,
    const float* __restrict__ wv, const float* __restrict__ bv,
    const float* __restrict__ wo, const float* __restrict__ bo,
    const float* __restrict__ wfc, const float* __restrict__ bfc,
    float* __restrict__ out)
{
  __shared__ float H[NODES*33];
  __shared__ float K[NODES*33];
  __shared__ float V[NODES*33];
  __shared__ float Wq[HID*HID];
  __shared__ float Wo[HID*HID];
  __shared__ float Wfc[192*6];
  __shared__ float Qs[6*33];
  __shared__ float S[6*56];
  __shared__ float O[6*33];
  __shared__ float SO[192];
  __shared__ float part[96];
  __shared__ float M[NODES];
  __shared__ int order[8];
  __shared__ int sel[6];

  int g = blockIdx.x, t = threadIdx.x;
  for (int i=t; i<HID*HID; i+=256){ Wq[i]=wq[i]; Wo[i]=wo[i]; }
  for (int i=t; i<192*6;   i+=256){ Wfc[i]=wfc[i]; }
  {
    const f16x8* j8 = (const f16x8*)(jk + (size_t)g*NODES*HID);
    for (int i=t; i<NODES*HID/8; i+=256){     // 220 vectors of 8
      f16x8 v = j8[i];
      int node = i >> 2, c0 = (i & 3)*8;
      #pragma unroll
      for (int r=0;r<8;r++) H[node*33 + c0 + r] = selu_f((float)v[r]);
    }
  }
  if (t < NODES) M[t] = x[(size_t)(g*NODES+t)*INCH + (INCH-3)];
  __syncthreads();
  if (t == 0){
    int c = 0;
    for (int n=0;n<NODES;n++) if (M[n] > 0.5f && c < 6) order[c++] = n;
  }
  __syncthreads();
  if (t < 6) sel[t] = order[shuf[g*6 + t]];
  __syncthreads();

  // K and V: lane = node, wave-uniform output-channel group -> scalar weights
  {
    int k = t & 63;
    int ocg = __builtin_amdgcn_readfirstlane(t >> 6);   // 0..3, wave-uniform
    const float* wkp = wk + ocg*8;
    const float* wvp = wv + ocg*8;
    if (k < NODES){
      float ak[8], av[8];
      #pragma unroll
      for (int j=0;j<8;j++){ ak[j]=bk[ocg*8+j]; av[j]=bv[ocg*8+j]; }
      #pragma unroll
      for (int c=0;c<HID;c++){
        float hv = H[k*33+c];
        #pragma unroll
        for (int j=0;j<8;j++){
          ak[j] = fmaf(hv, wkp[c*HID+j], ak[j]);
          av[j] = fmaf(hv, wvp[c*HID+j], av[j]);
        }
      }
      #pragma unroll
      for (int j=0;j<8;j++){ K[k*33+ocg*8+j]=ak[j]; V[k*33+ocg*8+j]=av[j]; }
    }
  }
  // Q: 6 queries x 32 channels
  if (t < 192){
    int q = t>>5, oc = t&31;
    int node = sel[q];
    float a = bq[oc];
    #pragma unroll
    for (int c=0;c<HID;c++) a = fmaf(H[node*33+c], Wq[c*HID+oc], a);
    Qs[q*33+oc] = a;
  }
  __syncthreads();

  // scores = Q.K^T / sqrt(32)
  for (int idx=t; idx<6*NODES; idx+=256){
    int q = idx % 6, k = idx / 6;
    float a = 0.f;
    #pragma unroll
    for (int c=0;c<HID;c++) a = fmaf(Qs[q*33+c], K[k*33+c], a);
    S[q*56+k] = a * 0.17677669529663687f;
  }
  __syncthreads();

  // softmax over 55 keys: 32-lane group per query
  if (t < 192){
    int q = t>>5, l = t&31;
    float v0 = (l      < NODES) ? S[q*56+l]    : -1e30f;
    float v1 = (l+32   < NODES) ? S[q*56+l+32] : -1e30f;
    float mx = fmaxf(v0, v1);
    #pragma unroll
    for (int o=16;o>0;o>>=1) mx = fmaxf(mx, __shfl_xor(mx, o, 32));
    float p0 = (l    < NODES) ? __expf(v0-mx) : 0.f;
    float p1 = (l+32 < NODES) ? __expf(v1-mx) : 0.f;
    float sm = p0 + p1;
    #pragma unroll
    for (int o=16;o>0;o>>=1) sm += __shfl_xor(sm, o, 32);
    float inv = 1.f/sm;
    if (l    < NODES) S[q*56+l]    = p0*inv;
    if (l+32 < NODES) S[q*56+l+32] = p1*inv;
  }
  __syncthreads();

  // attn @ V
  if (t < 192){
    int q = t>>5, oc = t&31;
    float a = 0.f;
    for (int k=0;k<NODES;k++) a = fmaf(S[q*56+k], V[k*33+oc], a);
    O[q*33+oc] = a;
  }
  __syncthreads();

  // @ wo + bo, selu
  if (t < 192){
    int q = t>>5, oc = t&31;
    float a = bo[oc];
    #pragma unroll
    for (int c=0;c<HID;c++) a = fmaf(O[q*33+c], Wo[c*HID+oc], a);
    SO[t] = selu_f(a);   // t == q*32+oc == flat reshape index
  }
  __syncthreads();

  // final FC: 6 outputs = SO[192] . Wfc[:,j]
  if (t < 96){
    int j = t % 6, pp = t / 6;   // 16 partials per output
    float a = 0.f;
    #pragma unroll
    for (int r=0;r<12;r++) a = fmaf(SO[pp*12+r], Wfc[(pp*12+r)*6+j], a);
    part[pp*6+j] = a;
  }
  __syncthreads();
  if (t < 6){
    float a = bfc[t];
    #pragma unroll
    for (int pp=0;pp<16;pp++) a += part[pp*6+t];
    out[g*6+t] = a;
  }
}

extern "C" void kernel_launch(void* const* d_in, const int* in_sizes, int n_in,
                              void* d_out, int out_size, void* d_ws, size_t ws_size,
                              hipStream_t stream)
{
  const float* x   = (const float*)d_in[0];
  const int*   eix = (const int*)d_in[1];
  const int*   shf = (const int*)d_in[2];
  const float* wl0 = (const float*)d_in[3];
  const float* bl0 = (const float*)d_in[4];
  const float* wr0 = (const float*)d_in[5];
  const float* wl  = (const float*)d_in[6];
  const float* bl  = (const float*)d_in[7];
  const float* wr  = (const float*)d_in[8];
  const float* wq  = (const float*)d_in[9];
  const float* bq  = (const float*)d_in[10];
  const float* wk  = (const float*)d_in[11];
  const float* bk  = (const float*)d_in[12];
  const float* wv  = (const float*)d_in[13];
  const float* bv  = (const float*)d_in[14];
  const float* wo  = (const float*)d_in[15];
  const float* bo  = (const float*)d_in[16];
  const float* wfc = (const float*)d_in[17];
  const float* bfc = (const float*)d_in[18];
  float* out = (float*)d_out;

  const int* esrc = eix;
  const int* edst = eix + ETOT;

  // workspace carve — total ~195 MB
  char* p = (char*)d_ws;
  auto carve = [&](size_t bytes){ void* r = (void*)p; p += (bytes + 255) & ~(size_t)255; return r; };
  int*      deg  = (int*)carve(sizeof(int)*NTOT);          // reused as `cur` for k_fill
  int*      off  = (int*)carve(sizeof(int)*(NTOT+1));
  int*      part = (int*)carve(sizeof(int)*1024);
  uint32_t* csrp = (uint32_t*)carve(sizeof(uint32_t)*(size_t)ETOT);
  f16*      h_a  = (f16*)carve(2*(size_t)NTOT*HID);
  f16*      h_b  = (f16*)carve(2*(size_t)NTOT*HID);
  f16*      jk16 = (f16*)carve(2*(size_t)NTOT*HID);

  hipMemsetAsync(deg, 0, sizeof(int)*NTOT, stream);
  k_hist <<<ETOT/256,  256, 0, stream>>>(edst, deg);
  k_scan1<<<NCHUNK,    256, 0, stream>>>(deg, part);
  k_scan2<<<1,        1024, 0, stream>>>(part, NCHUNK);
  k_scan3<<<NCHUNK,    256, 0, stream>>>(deg, part, off);
  // reuse deg as the fill cursor
  hipMemcpyAsync(deg, off, sizeof(int)*NTOT, hipMemcpyDeviceToDevice, stream);
  k_fill <<<ETOT/256,  256, 0, stream>>>(esrc, edst, deg, csrp);

  k_layer0<<<NTOT/NPB, 256, 0, stream>>>(x, off, csrp, wl0, bl0, wr0, h_a, jk16);
  f16* hc = h_a; f16* hn = h_b;
  for (int l=0; l<4; l++){
    k_layer<<<NTOT/NPB, 256, 0, stream>>>(hc, off, csrp,
                                          wl + l*HID*HID, bl + l*HID, wr + l*HID*HID,
                                          hn, jk16);
    f16* tmp = hc; hc = hn; hn = tmp;
  }
  k_attn<<<BGRAPH, 256, 0, stream>>>(jk16, x, shf,
                                     wq, bq, wk, bk, wv, bv, wo, bo, wfc, bfc, out);
}